// Round 1
// baseline (1725.996 us; speedup 1.0000x reference)
//
#include <hip/hip_runtime.h>

// CRF Viterbi decode: B=64, T=1024, K=256.
// emissions [B,T,K] f32, transitions [K,K] f32 (prev->next). out [B,T] f32 tags.

#define CRF_B 64
#define CRF_T 1024
#define CRF_K 256
#define GROUPS 4
#define PREV_PER 64   // CRF_K / GROUPS
#define CHUNKS 16     // PREV_PER / 4

// ---------------------------------------------------------------------------
// Path 1 (preferred): forward stores all state vectors; backtrack recomputes
// the single argmax per step (bit-identical floats, first-index tie-break).
// ---------------------------------------------------------------------------

__global__ __launch_bounds__(1024) void crf_forward_states(
    const float* __restrict__ em, const float* __restrict__ trans,
    float* __restrict__ states)
{
    const int b   = blockIdx.x;
    const int tid = threadIdx.x;
    const int g   = tid >> 8;     // group 0..3 -> prev range
    const int k   = tid & 255;    // next-tag

    __shared__ __align__(16) float s_state[CRF_K];
    __shared__ float s_partial[GROUPS][CRF_K];

    // Preload this thread's transition slice into registers:
    // tr[i].{x,y,z,w} = trans[(pbase+4i+j)*K + k]  (coalesced across k lanes)
    const int pbase = g * PREV_PER;
    float4 tr[CHUNKS];
#pragma unroll
    for (int i = 0; i < CHUNKS; ++i) {
        const int p = pbase + 4 * i;
        tr[i].x = trans[(p + 0) * CRF_K + k];
        tr[i].y = trans[(p + 1) * CRF_K + k];
        tr[i].z = trans[(p + 2) * CRF_K + k];
        tr[i].w = trans[(p + 3) * CRF_K + k];
    }

    const float* emb = em + (size_t)b * CRF_T * CRF_K;
    if (g == 0) {
        float v = emb[k];
        s_state[k] = v;
        states[(size_t)b * CRF_K + k] = v;   // t = 0 slot: ((0*B)+b)*K + k
    }
    __syncthreads();

    for (int t = 1; t < CRF_T; ++t) {
        float e = 0.0f;
        if (g == 0) e = emb[t * CRF_K + k];  // issue early; hidden by inner loop

        float best = -INFINITY;
        const float4* sp = (const float4*)(s_state + pbase);
#pragma unroll
        for (int i = 0; i < CHUNKS; ++i) {
            float4 st = sp[i];               // broadcast ds_read_b128
            float s0 = st.x + tr[i].x;
            float s1 = st.y + tr[i].y;
            float s2 = st.z + tr[i].z;
            float s3 = st.w + tr[i].w;
            best = fmaxf(best, fmaxf(fmaxf(s0, s1), fmaxf(s2, s3)));
        }
        s_partial[g][k] = best;
        __syncthreads();                     // all reads of s_state complete here
        if (g == 0) {
            float v = fmaxf(fmaxf(s_partial[0][k], s_partial[1][k]),
                            fmaxf(s_partial[2][k], s_partial[3][k])) + e;
            s_state[k] = v;
            states[((size_t)t * CRF_B + b) * CRF_K + k] = v;
        }
        __syncthreads();
    }
}

__global__ void crf_transpose_trans(const float* __restrict__ trans,
                                    float* __restrict__ Tt)
{
    // Tt[k][p] = trans[p][k]; 256 blocks x 256 threads (tiny, one-shot)
    const int k = blockIdx.x;
    const int p = threadIdx.x;
    Tt[(size_t)k * CRF_K + p] = trans[(size_t)p * CRF_K + k];
}

__global__ void crf_backtrack_states(
    const float* __restrict__ states, const float* __restrict__ Tt,
    float* __restrict__ out)
{
    const int b    = blockIdx.x;
    const int lane = threadIdx.x;   // 64 threads = 1 wave
    const int base = lane * 4;

    // last tag = argmax over final state (first-index tie-break)
    const float4* stb =
        (const float4*)(states + ((size_t)(CRF_T - 1) * CRF_B + b) * CRF_K);
    float4 v = stb[lane];
    float bv = v.x; int bi = base;
    if (v.y > bv) { bv = v.y; bi = base + 1; }
    if (v.z > bv) { bv = v.z; bi = base + 2; }
    if (v.w > bv) { bv = v.w; bi = base + 3; }
#pragma unroll
    for (int off = 32; off >= 1; off >>= 1) {
        float ov = __shfl_xor(bv, off, 64);
        int   oi = __shfl_xor(bi, off, 64);
        if (ov > bv || (ov == bv && oi < bi)) { bv = ov; bi = oi; }
    }
    int tag = bi;   // all lanes agree (semilattice combine)
    if (lane == 0) out[(size_t)b * CRF_T + (CRF_T - 1)] = (float)tag;

    for (int t = CRF_T - 1; t >= 1; --t) {
        const float4* st =
            (const float4*)(states + ((size_t)(t - 1) * CRF_B + b) * CRF_K);
        float4 sv = st[lane];                         // not on the tag chain
        const float4* tt = (const float4*)(Tt + (size_t)tag * CRF_K);
        float4 tv = tt[lane];                         // coalesced row, L2-hot
        float s0 = sv.x + tv.x, s1 = sv.y + tv.y;
        float s2 = sv.z + tv.z, s3 = sv.w + tv.w;
        float nbv = s0; int nbi = base;
        if (s1 > nbv) { nbv = s1; nbi = base + 1; }
        if (s2 > nbv) { nbv = s2; nbi = base + 2; }
        if (s3 > nbv) { nbv = s3; nbi = base + 3; }
#pragma unroll
        for (int off = 32; off >= 1; off >>= 1) {
            float ov = __shfl_xor(nbv, off, 64);
            int   oi = __shfl_xor(nbi, off, 64);
            if (ov > nbv || (ov == nbv && oi < nbi)) { nbv = ov; nbi = oi; }
        }
        tag = nbi;
        if (lane == 0) out[(size_t)b * CRF_T + (t - 1)] = (float)tag;
    }
}

// ---------------------------------------------------------------------------
// Path 2 (fallback if ws too small): store uint8 backpointers (16.8 MB).
// ---------------------------------------------------------------------------

__global__ __launch_bounds__(1024) void crf_forward_bp(
    const float* __restrict__ em, const float* __restrict__ trans,
    unsigned char* __restrict__ bp, int* __restrict__ last_tag)
{
    const int b   = blockIdx.x;
    const int tid = threadIdx.x;
    const int g   = tid >> 8;
    const int k   = tid & 255;

    __shared__ __align__(16) float s_state[CRF_K];
    __shared__ float s_pb[GROUPS][CRF_K];
    __shared__ int   s_pa[GROUPS][CRF_K];

    const int pbase = g * PREV_PER;
    float4 tr[CHUNKS];
#pragma unroll
    for (int i = 0; i < CHUNKS; ++i) {
        const int p = pbase + 4 * i;
        tr[i].x = trans[(p + 0) * CRF_K + k];
        tr[i].y = trans[(p + 1) * CRF_K + k];
        tr[i].z = trans[(p + 2) * CRF_K + k];
        tr[i].w = trans[(p + 3) * CRF_K + k];
    }

    const float* emb = em + (size_t)b * CRF_T * CRF_K;
    if (g == 0) s_state[k] = emb[k];
    __syncthreads();

    for (int t = 1; t < CRF_T; ++t) {
        float e = 0.0f;
        if (g == 0) e = emb[t * CRF_K + k];

        float best = -INFINITY;
        int   arg  = pbase;
        const float4* sp = (const float4*)(s_state + pbase);
#pragma unroll
        for (int i = 0; i < CHUNKS; ++i) {
            float4 st = sp[i];
            const int p = pbase + 4 * i;
            float s0 = st.x + tr[i].x;
            float s1 = st.y + tr[i].y;
            float s2 = st.z + tr[i].z;
            float s3 = st.w + tr[i].w;
            if (s0 > best) { best = s0; arg = p; }
            if (s1 > best) { best = s1; arg = p + 1; }
            if (s2 > best) { best = s2; arg = p + 2; }
            if (s3 > best) { best = s3; arg = p + 3; }
        }
        s_pb[g][k] = best;
        s_pa[g][k] = arg;
        __syncthreads();
        if (g == 0) {
            float bbest = s_pb[0][k];
            int   barg  = s_pa[0][k];
#pragma unroll
            for (int j = 1; j < GROUPS; ++j) {
                float pb = s_pb[j][k];
                if (pb > bbest) { bbest = pb; barg = s_pa[j][k]; }
            }
            bp[((size_t)(t - 1) * CRF_B + b) * CRF_K + k] = (unsigned char)barg;
            s_state[k] = bbest + e;
        }
        __syncthreads();
    }

    if (tid == 0) {
        float bv = s_state[0]; int bi = 0;
        for (int j = 1; j < CRF_K; ++j) {
            float v = s_state[j];
            if (v > bv) { bv = v; bi = j; }
        }
        last_tag[b] = bi;
    }
}

__global__ void crf_backtrack_bp(const unsigned char* __restrict__ bp,
                                 const int* __restrict__ last_tag,
                                 float* __restrict__ out)
{
    const int b = threadIdx.x;   // 1 block x 64 threads
    if (b >= CRF_B) return;
    int tag = last_tag[b];
    out[(size_t)b * CRF_T + (CRF_T - 1)] = (float)tag;
    for (int t = CRF_T - 2; t >= 0; --t) {
        tag = bp[((size_t)t * CRF_B + b) * CRF_K + tag];
        out[(size_t)b * CRF_T + t] = (float)tag;
    }
}

__global__ void crf_zero_out(float* __restrict__ out, int n)
{
    int i = blockIdx.x * blockDim.x + threadIdx.x;
    if (i < n) out[i] = 0.0f;
}

// ---------------------------------------------------------------------------

extern "C" void kernel_launch(void* const* d_in, const int* in_sizes, int n_in,
                              void* d_out, int out_size, void* d_ws, size_t ws_size,
                              hipStream_t stream) {
    (void)in_sizes; (void)n_in;
    const float* em    = (const float*)d_in[0];   // [B,T,K]
    const float* trans = (const float*)d_in[1];   // [K,K]
    float* out = (float*)d_out;                   // [B,T]

    const size_t states_bytes = (size_t)CRF_T * CRF_B * CRF_K * sizeof(float); // 64 MB
    const size_t tt_bytes     = (size_t)CRF_K * CRF_K * sizeof(float);         // 256 KB
    const size_t bp_bytes     = (size_t)(CRF_T - 1) * CRF_B * CRF_K;           // ~16.8 MB

    if (ws_size >= states_bytes + tt_bytes) {
        float* states = (float*)d_ws;
        float* Tt     = (float*)((char*)d_ws + states_bytes);
        crf_transpose_trans<<<CRF_K, CRF_K, 0, stream>>>(trans, Tt);
        crf_forward_states<<<CRF_B, 1024, 0, stream>>>(em, trans, states);
        crf_backtrack_states<<<CRF_B, 64, 0, stream>>>(states, Tt, out);
    } else if (ws_size >= bp_bytes + CRF_B * sizeof(int)) {
        unsigned char* bp = (unsigned char*)d_ws;
        int* last_tag     = (int*)((char*)d_ws + bp_bytes);
        crf_forward_bp<<<CRF_B, 1024, 0, stream>>>(em, trans, bp, last_tag);
        crf_backtrack_bp<<<1, 64, 0, stream>>>(bp, last_tag, out);
    } else {
        // no usable workspace: fail visibly rather than crash
        crf_zero_out<<<(out_size + 255) / 256, 256, 0, stream>>>(out, out_size);
    }
}

// Round 2
// 1534.204 us; speedup vs baseline: 1.1250x; 1.1250x over previous
//
#include <hip/hip_runtime.h>

// CRF Viterbi decode: B=64, T=1024, K=256.
// emissions [B,T,K] f32, transitions [K,K] f32 (prev->next). out [B,T] f32 tags.

#define CRF_B 64
#define CRF_T 1024
#define CRF_K 256

// Forward decomposition: 1024 threads = 8 prev-groups x 128 col-threads,
// each col-thread owns 2 next-tag columns (c and c+128) and 32 prevs.
#define FG 8        // prev groups
#define FP 32       // prevs per group
#define FC 8        // float4 chunks per group (FP/4)

// ---------------------------------------------------------------------------
// Forward: stores all state vectors to d_ws (64 MB). Backtrack recomputes the
// single needed argmax per step (bit-identical floats, first-index ties).
// ---------------------------------------------------------------------------

__global__ __launch_bounds__(1024) void crf_forward_states(
    const float* __restrict__ em, const float* __restrict__ trans,
    float* __restrict__ states)
{
    const int b   = blockIdx.x;
    const int tid = threadIdx.x;
    const int g   = tid >> 7;      // prev group 0..7
    const int c   = tid & 127;     // columns c and c+128

    __shared__ __align__(16) float s_state[CRF_K];
    __shared__ float s_partial[FG][CRF_K];

    const int pbase = g * FP;

    // Preload this thread's transition slices into registers.
    float4 t0[FC], t1[FC];
#pragma unroll
    for (int i = 0; i < FC; ++i) {
        const int p = pbase + 4 * i;
        t0[i].x = trans[(p + 0) * CRF_K + c];
        t0[i].y = trans[(p + 1) * CRF_K + c];
        t0[i].z = trans[(p + 2) * CRF_K + c];
        t0[i].w = trans[(p + 3) * CRF_K + c];
        t1[i].x = trans[(p + 0) * CRF_K + c + 128];
        t1[i].y = trans[(p + 1) * CRF_K + c + 128];
        t1[i].z = trans[(p + 2) * CRF_K + c + 128];
        t1[i].w = trans[(p + 3) * CRF_K + c + 128];
    }
    // Pin them: opaque asm blocks load-rematerialization inside the t-loop
    // (the round-1 build showed VGPR_Count=48 -> trans was re-fetched/step).
#pragma unroll
    for (int i = 0; i < FC; ++i) {
        asm volatile("" : "+v"(t0[i].x), "+v"(t0[i].y), "+v"(t0[i].z), "+v"(t0[i].w));
        asm volatile("" : "+v"(t1[i].x), "+v"(t1[i].y), "+v"(t1[i].z), "+v"(t1[i].w));
    }

    const float* emb = em + (size_t)b * CRF_T * CRF_K;
    if (tid < CRF_K) {
        float v = emb[tid];
        s_state[tid] = v;
        states[(size_t)b * CRF_K + tid] = v;   // t = 0
    }
    __syncthreads();

    for (int t = 1; t < CRF_T; ++t) {
        float e = 0.0f;
        if (tid < CRF_K) e = emb[t * CRF_K + tid];   // consumed after barrier

        float b0 = -INFINITY, b1 = -INFINITY;
        const float4* sp = (const float4*)(s_state + pbase);
#pragma unroll
        for (int i = 0; i < FC; ++i) {
            float4 st = sp[i];                       // broadcast ds_read_b128
            float a0 = st.x + t0[i].x;
            float a1 = st.y + t0[i].y;
            float a2 = st.z + t0[i].z;
            float a3 = st.w + t0[i].w;
            b0 = fmaxf(b0, fmaxf(fmaxf(a0, a1), fmaxf(a2, a3)));
            float c0 = st.x + t1[i].x;
            float c1 = st.y + t1[i].y;
            float c2 = st.z + t1[i].z;
            float c3 = st.w + t1[i].w;
            b1 = fmaxf(b1, fmaxf(fmaxf(c0, c1), fmaxf(c2, c3)));
        }
        s_partial[g][c]       = b0;
        s_partial[g][c + 128] = b1;
        __syncthreads();
        if (tid < CRF_K) {
            float m = s_partial[0][tid];
#pragma unroll
            for (int j = 1; j < FG; ++j) m = fmaxf(m, s_partial[j][tid]);
            float v = m + e;
            s_state[tid] = v;
            states[((size_t)t * CRF_B + b) * CRF_K + tid] = v;
        }
        __syncthreads();
    }
}

__global__ void crf_transpose_trans(const float* __restrict__ trans,
                                    float* __restrict__ Tt)
{
    const int k = blockIdx.x;
    const int p = threadIdx.x;
    Tt[(size_t)k * CRF_K + p] = trans[(size_t)p * CRF_K + k];
}

// ---------------------------------------------------------------------------
// Backtrack: 64 blocks x 1 wave. Per step: tag-independent state row is
// prefetched 4-deep; only the Tt row load (L2-hot) sits on the tag chain.
// ---------------------------------------------------------------------------

__device__ __forceinline__ int wave_argmax(float v, int i)
{
    // (max value, first index) over 64 lanes; all lanes return the index.
#pragma unroll
    for (int off = 32; off >= 1; off >>= 1) {
        float ov = __shfl_xor(v, off, 64);
        int   oi = __shfl_xor(i, off, 64);
        if (ov > v || (ov == v && oi < i)) { v = ov; i = oi; }
    }
    return i;
}

__device__ __forceinline__ int step_argmax(float4 sv, float4 tv, int base)
{
    float s0 = sv.x + tv.x, s1 = sv.y + tv.y;
    float s2 = sv.z + tv.z, s3 = sv.w + tv.w;
    float nbv = s0; int nbi = base;
    if (s1 > nbv) { nbv = s1; nbi = base + 1; }
    if (s2 > nbv) { nbv = s2; nbi = base + 2; }
    if (s3 > nbv) { nbv = s3; nbi = base + 3; }
    return wave_argmax(nbv, nbi);
}

__global__ __launch_bounds__(64) void crf_backtrack_states(
    const float* __restrict__ states, const float* __restrict__ Tt,
    float* __restrict__ out)
{
    const int b    = blockIdx.x;
    const int lane = threadIdx.x;
    const int base = lane * 4;

    // last tag = argmax over final state
    const float4* stb =
        (const float4*)(states + ((size_t)(CRF_T - 1) * CRF_B + b) * CRF_K);
    float4 v = stb[lane];
    float bv = v.x; int bi = base;
    if (v.y > bv) { bv = v.y; bi = base + 1; }
    if (v.z > bv) { bv = v.z; bi = base + 2; }
    if (v.w > bv) { bv = v.w; bi = base + 3; }
    int tag = wave_argmax(bv, bi);
    if (lane == 0) out[(size_t)b * CRF_T + (CRF_T - 1)] = (float)tag;

    float* ob = out + (size_t)b * CRF_T;

    // main loop: t = 1023 .. 4, unrolled by 4 with state rows prefetched
    int t = CRF_T - 1;
    for (; t >= 4; t -= 4) {
        // prefetch the 4 tag-independent state rows (t-1 .. t-4)
        const float4* r0 = (const float4*)(states + ((size_t)(t - 1) * CRF_B + b) * CRF_K);
        const float4* r1 = (const float4*)(states + ((size_t)(t - 2) * CRF_B + b) * CRF_K);
        const float4* r2 = (const float4*)(states + ((size_t)(t - 3) * CRF_B + b) * CRF_K);
        const float4* r3 = (const float4*)(states + ((size_t)(t - 4) * CRF_B + b) * CRF_K);
        float4 sv0 = r0[lane];
        float4 sv1 = r1[lane];
        float4 sv2 = r2[lane];
        float4 sv3 = r3[lane];

        float4 tv = ((const float4*)(Tt + (size_t)tag * CRF_K))[lane];
        tag = step_argmax(sv0, tv, base);
        if (lane == 0) ob[t - 1] = (float)tag;

        tv = ((const float4*)(Tt + (size_t)tag * CRF_K))[lane];
        tag = step_argmax(sv1, tv, base);
        if (lane == 0) ob[t - 2] = (float)tag;

        tv = ((const float4*)(Tt + (size_t)tag * CRF_K))[lane];
        tag = step_argmax(sv2, tv, base);
        if (lane == 0) ob[t - 3] = (float)tag;

        tv = ((const float4*)(Tt + (size_t)tag * CRF_K))[lane];
        tag = step_argmax(sv3, tv, base);
        if (lane == 0) ob[t - 4] = (float)tag;
    }
    for (; t >= 1; --t) {
        const float4* r =
            (const float4*)(states + ((size_t)(t - 1) * CRF_B + b) * CRF_K);
        float4 sv = r[lane];
        float4 tv = ((const float4*)(Tt + (size_t)tag * CRF_K))[lane];
        tag = step_argmax(sv, tv, base);
        if (lane == 0) ob[t - 1] = (float)tag;
    }
}

// ---------------------------------------------------------------------------
// Fallback path (ws too small): uint8 backpointers (16.8 MB).
// ---------------------------------------------------------------------------

__global__ __launch_bounds__(1024) void crf_forward_bp(
    const float* __restrict__ em, const float* __restrict__ trans,
    unsigned char* __restrict__ bp, int* __restrict__ last_tag)
{
    const int b   = blockIdx.x;
    const int tid = threadIdx.x;
    const int g   = tid >> 8;
    const int k   = tid & 255;

    __shared__ __align__(16) float s_state[CRF_K];
    __shared__ float s_pb[4][CRF_K];
    __shared__ int   s_pa[4][CRF_K];

    const int pbase = g * 64;
    float4 tr[16];
#pragma unroll
    for (int i = 0; i < 16; ++i) {
        const int p = pbase + 4 * i;
        tr[i].x = trans[(p + 0) * CRF_K + k];
        tr[i].y = trans[(p + 1) * CRF_K + k];
        tr[i].z = trans[(p + 2) * CRF_K + k];
        tr[i].w = trans[(p + 3) * CRF_K + k];
        asm volatile("" : "+v"(tr[i].x), "+v"(tr[i].y), "+v"(tr[i].z), "+v"(tr[i].w));
    }

    const float* emb = em + (size_t)b * CRF_T * CRF_K;
    if (g == 0) s_state[k] = emb[k];
    __syncthreads();

    for (int t = 1; t < CRF_T; ++t) {
        float e = 0.0f;
        if (g == 0) e = emb[t * CRF_K + k];

        float best = -INFINITY;
        int   arg  = pbase;
        const float4* sp = (const float4*)(s_state + pbase);
#pragma unroll
        for (int i = 0; i < 16; ++i) {
            float4 st = sp[i];
            const int p = pbase + 4 * i;
            float s0 = st.x + tr[i].x;
            float s1 = st.y + tr[i].y;
            float s2 = st.z + tr[i].z;
            float s3 = st.w + tr[i].w;
            if (s0 > best) { best = s0; arg = p; }
            if (s1 > best) { best = s1; arg = p + 1; }
            if (s2 > best) { best = s2; arg = p + 2; }
            if (s3 > best) { best = s3; arg = p + 3; }
        }
        s_pb[g][k] = best;
        s_pa[g][k] = arg;
        __syncthreads();
        if (g == 0) {
            float bbest = s_pb[0][k];
            int   barg  = s_pa[0][k];
#pragma unroll
            for (int j = 1; j < 4; ++j) {
                float pb = s_pb[j][k];
                if (pb > bbest) { bbest = pb; barg = s_pa[j][k]; }
            }
            bp[((size_t)(t - 1) * CRF_B + b) * CRF_K + k] = (unsigned char)barg;
            s_state[k] = bbest + e;
        }
        __syncthreads();
    }

    if (tid == 0) {
        float bv = s_state[0]; int bi = 0;
        for (int j = 1; j < CRF_K; ++j) {
            float v = s_state[j];
            if (v > bv) { bv = v; bi = j; }
        }
        last_tag[b] = bi;
    }
}

__global__ void crf_backtrack_bp(const unsigned char* __restrict__ bp,
                                 const int* __restrict__ last_tag,
                                 float* __restrict__ out)
{
    const int b = threadIdx.x;
    if (b >= CRF_B) return;
    int tag = last_tag[b];
    out[(size_t)b * CRF_T + (CRF_T - 1)] = (float)tag;
    for (int t = CRF_T - 2; t >= 0; --t) {
        tag = bp[((size_t)t * CRF_B + b) * CRF_K + tag];
        out[(size_t)b * CRF_T + t] = (float)tag;
    }
}

__global__ void crf_zero_out(float* __restrict__ out, int n)
{
    int i = blockIdx.x * blockDim.x + threadIdx.x;
    if (i < n) out[i] = 0.0f;
}

// ---------------------------------------------------------------------------

extern "C" void kernel_launch(void* const* d_in, const int* in_sizes, int n_in,
                              void* d_out, int out_size, void* d_ws, size_t ws_size,
                              hipStream_t stream) {
    (void)in_sizes; (void)n_in;
    const float* em    = (const float*)d_in[0];   // [B,T,K]
    const float* trans = (const float*)d_in[1];   // [K,K]
    float* out = (float*)d_out;                   // [B,T]

    const size_t states_bytes = (size_t)CRF_T * CRF_B * CRF_K * sizeof(float); // 64 MB
    const size_t tt_bytes     = (size_t)CRF_K * CRF_K * sizeof(float);         // 256 KB
    const size_t bp_bytes     = (size_t)(CRF_T - 1) * CRF_B * CRF_K;           // ~16.8 MB

    if (ws_size >= states_bytes + tt_bytes) {
        float* states = (float*)d_ws;
        float* Tt     = (float*)((char*)d_ws + states_bytes);
        crf_transpose_trans<<<CRF_K, CRF_K, 0, stream>>>(trans, Tt);
        crf_forward_states<<<CRF_B, 1024, 0, stream>>>(em, trans, states);
        crf_backtrack_states<<<CRF_B, 64, 0, stream>>>(states, Tt, out);
    } else if (ws_size >= bp_bytes + CRF_B * sizeof(int)) {
        unsigned char* bp = (unsigned char*)d_ws;
        int* last_tag     = (int*)((char*)d_ws + bp_bytes);
        crf_forward_bp<<<CRF_B, 1024, 0, stream>>>(em, trans, bp, last_tag);
        crf_backtrack_bp<<<1, 64, 0, stream>>>(bp, last_tag, out);
    } else {
        crf_zero_out<<<(out_size + 255) / 256, 256, 0, stream>>>(out, out_size);
    }
}

// Round 4
// 1447.824 us; speedup vs baseline: 1.1921x; 1.0597x over previous
//
#include <hip/hip_runtime.h>

// CRF Viterbi decode: B=64, T=1024, K=256.
// emissions [B,T,K] f32, transitions [K,K] f32 (prev->next). out [B,T] f32 tags.
//
// Path A (needs states 64MB + bp 16MB = 80.25MB ws):
//   1. crf_forward_states : PROVEN round-2 kernel (bit-exact revert). Stores all
//      state vectors [T,B,K] f32.
//   2. crf_bp_matrix      : parallel over (b,seg) on all 256 CUs: recompute
//      argmax backpointers bp[b][t][k] (u8) from stored states.
//   3. crf_backtrack      : one block per b: segmented chase entirely in LDS
//      (maps -> compose -> re-chase), no cross-kernel scratch beyond bp.
// Path B fallback (64.25MB): round-2 proven transpose+forward+serial backtrack.

#define CRF_B 64
#define CRF_T 1024
#define CRF_K 256
#define NSEG  16
#define SEGLEN 64

// Forward decomposition (round-2 exact): 1024 threads = 8 prev-groups x 128
// col-threads, each col-thread owns 2 next-tag columns (c, c+128), 32 prevs.
#define FG 8
#define FP 32
#define FC 8

// ---------------------------------------------------------------------------
// Forward (PROVEN round-2 version — do not touch)
// ---------------------------------------------------------------------------

__global__ __launch_bounds__(1024) void crf_forward_states(
    const float* __restrict__ em, const float* __restrict__ trans,
    float* __restrict__ states)
{
    const int b   = blockIdx.x;
    const int tid = threadIdx.x;
    const int g   = tid >> 7;      // prev group 0..7
    const int c   = tid & 127;     // columns c and c+128

    __shared__ __align__(16) float s_state[CRF_K];
    __shared__ float s_partial[FG][CRF_K];

    const int pbase = g * FP;

    float4 t0[FC], t1[FC];
#pragma unroll
    for (int i = 0; i < FC; ++i) {
        const int p = pbase + 4 * i;
        t0[i].x = trans[(p + 0) * CRF_K + c];
        t0[i].y = trans[(p + 1) * CRF_K + c];
        t0[i].z = trans[(p + 2) * CRF_K + c];
        t0[i].w = trans[(p + 3) * CRF_K + c];
        t1[i].x = trans[(p + 0) * CRF_K + c + 128];
        t1[i].y = trans[(p + 1) * CRF_K + c + 128];
        t1[i].z = trans[(p + 2) * CRF_K + c + 128];
        t1[i].w = trans[(p + 3) * CRF_K + c + 128];
    }
#pragma unroll
    for (int i = 0; i < FC; ++i) {
        asm volatile("" : "+v"(t0[i].x), "+v"(t0[i].y), "+v"(t0[i].z), "+v"(t0[i].w));
        asm volatile("" : "+v"(t1[i].x), "+v"(t1[i].y), "+v"(t1[i].z), "+v"(t1[i].w));
    }

    const float* emb = em + (size_t)b * CRF_T * CRF_K;
    if (tid < CRF_K) {
        float v = emb[tid];
        s_state[tid] = v;
        states[(size_t)b * CRF_K + tid] = v;   // t = 0
    }
    __syncthreads();

    for (int t = 1; t < CRF_T; ++t) {
        float e = 0.0f;
        if (tid < CRF_K) e = emb[t * CRF_K + tid];

        float b0 = -INFINITY, b1 = -INFINITY;
        const float4* sp = (const float4*)(s_state + pbase);
#pragma unroll
        for (int i = 0; i < FC; ++i) {
            float4 st = sp[i];
            float a0 = st.x + t0[i].x;
            float a1 = st.y + t0[i].y;
            float a2 = st.z + t0[i].z;
            float a3 = st.w + t0[i].w;
            b0 = fmaxf(b0, fmaxf(fmaxf(a0, a1), fmaxf(a2, a3)));
            float c0 = st.x + t1[i].x;
            float c1 = st.y + t1[i].y;
            float c2 = st.z + t1[i].z;
            float c3 = st.w + t1[i].w;
            b1 = fmaxf(b1, fmaxf(fmaxf(c0, c1), fmaxf(c2, c3)));
        }
        s_partial[g][c]       = b0;
        s_partial[g][c + 128] = b1;
        __syncthreads();
        if (tid < CRF_K) {
            float m = s_partial[0][tid];
#pragma unroll
            for (int j = 1; j < FG; ++j) m = fmaxf(m, s_partial[j][tid]);
            float v = m + e;
            s_state[tid] = v;
            states[((size_t)t * CRF_B + b) * CRF_K + tid] = v;
        }
        __syncthreads();
    }
}

// ---------------------------------------------------------------------------
// Backpointer matrix (NEW): 1024 blocks (b x 16 segs) x 1024 thr = 4 groups x
// 256 cols, 64 prevs/group. bp[b][t1][k] = argmax_p(states[t1][b][p]+T[p][k]).
// Ascending strict-> scan within group, ascending strict-> across groups
// = global first-index tie-break (matches jnp.argmax). Adds are bit-identical
// to forward's (same two operands).
// ---------------------------------------------------------------------------

__global__ __launch_bounds__(1024, 2) void crf_bp_matrix(
    const float* __restrict__ states, const float* __restrict__ trans,
    unsigned char* __restrict__ bp)
{
    const int b   = blockIdx.x >> 4;
    const int seg = blockIdx.x & 15;
    const int tid = threadIdx.x;
    const int g   = tid >> 8;      // 0..3
    const int k   = tid & 255;

    __shared__ __align__(16) float s_row[CRF_K];
    __shared__ float s_pv[4][CRF_K];
    __shared__ int   s_pi[4][CRF_K];

    const int pbase = g * 64;
    float4 tr[16];
#pragma unroll
    for (int i = 0; i < 16; ++i) {
        const int p = pbase + 4 * i;
        tr[i].x = trans[(p + 0) * CRF_K + k];
        tr[i].y = trans[(p + 1) * CRF_K + k];
        tr[i].z = trans[(p + 2) * CRF_K + k];
        tr[i].w = trans[(p + 3) * CRF_K + k];
        asm volatile("" : "+v"(tr[i].x), "+v"(tr[i].y), "+v"(tr[i].z), "+v"(tr[i].w));
    }

    const int t_lo = seg * SEGLEN;
    const int t_hi = min(t_lo + SEGLEN, CRF_T - 1);   // bp rows 0..1022

    unsigned char* bpb = bp + (size_t)b * (CRF_T - 1) * CRF_K;

    for (int t1 = t_lo; t1 < t_hi; ++t1) {
        if (tid < CRF_K)
            s_row[tid] = states[((size_t)t1 * CRF_B + b) * CRF_K + tid];
        __syncthreads();

        float best = -INFINITY;
        int   arg  = pbase;
        const float4* sp = (const float4*)(s_row + pbase);
#pragma unroll
        for (int i = 0; i < 16; ++i) {
            float4 st = sp[i];
            const int p = pbase + 4 * i;
            float s0 = st.x + tr[i].x;
            float s1 = st.y + tr[i].y;
            float s2 = st.z + tr[i].z;
            float s3 = st.w + tr[i].w;
            if (s0 > best) { best = s0; arg = p; }
            if (s1 > best) { best = s1; arg = p + 1; }
            if (s2 > best) { best = s2; arg = p + 2; }
            if (s3 > best) { best = s3; arg = p + 3; }
        }
        s_pv[g][k] = best;
        s_pi[g][k] = arg;
        __syncthreads();
        if (tid < CRF_K) {
            float bv = s_pv[0][tid];
            int   ba = s_pi[0][tid];
#pragma unroll
            for (int j = 1; j < 4; ++j) {
                float v = s_pv[j][tid];
                if (v > bv) { bv = v; ba = s_pi[j][tid]; }
            }
            bpb[(size_t)t1 * CRF_K + tid] = (unsigned char)ba;
        }
        __syncthreads();
    }
}

// ---------------------------------------------------------------------------
// Backtrack (NEW): 64 blocks x 256 thr. All composition inside one block:
//  P1: per segment, chase all 256 candidates via LDS bp rows -> entry map.
//  P2: last-tag argmax + compose per-segment exit tags.
//  P3: re-chase; winner thread writes tags.
// ---------------------------------------------------------------------------

__global__ __launch_bounds__(256) void crf_backtrack(
    const float* __restrict__ states, const unsigned char* __restrict__ bp,
    float* __restrict__ out)
{
    const int b   = blockIdx.x;
    const int tid = threadIdx.x;

    __shared__ unsigned char lbp[SEGLEN][CRF_K];   // 16 KB
    __shared__ unsigned char lmap[NSEG][CRF_K];    // 4 KB
    __shared__ int   s_E[NSEG];
    __shared__ float s_wv[4];
    __shared__ int   s_wi[4];

    const unsigned char* bpb = bp + (size_t)b * (CRF_T - 1) * CRF_K;

    // Phase 1: segment entry-maps
    for (int s = 0; s < NSEG; ++s) {
        const int rows = (s == NSEG - 1) ? SEGLEN - 1 : SEGLEN;
        const int r0   = s * SEGLEN;
        const int nw   = rows * 64;
        for (int w = tid; w < nw; w += 256) {
            const int r = w >> 6, cc = w & 63;
            ((unsigned int*)lbp[r])[cc] =
                ((const unsigned int*)(bpb + (size_t)(r0 + r) * CRF_K))[cc];
        }
        __syncthreads();
        int tag = tid;
        for (int j = rows - 1; j >= 0; --j) tag = lbp[j][tag];
        lmap[s][tid] = (unsigned char)tag;
        __syncthreads();   // lbp reuse + lmap completeness
    }

    // Phase 2: last tag (first-index argmax) + segment-exit composition
    float v = states[((size_t)(CRF_T - 1) * CRF_B + b) * CRF_K + tid];
    int   i = tid;
#pragma unroll
    for (int off = 32; off >= 1; off >>= 1) {
        float ov = __shfl_xor(v, off, 64);
        int   oi = __shfl_xor(i, off, 64);
        if (ov > v || (ov == v && oi < i)) { v = ov; i = oi; }
    }
    const int lane = tid & 63, wv = tid >> 6;
    if (lane == 0) { s_wv[wv] = v; s_wi[wv] = i; }
    __syncthreads();
    if (tid == 0) {
        float bv = s_wv[0]; int bi = s_wi[0];
#pragma unroll
        for (int w = 1; w < 4; ++w)
            if (s_wv[w] > bv) { bv = s_wv[w]; bi = s_wi[w]; }
        out[(size_t)b * CRF_T + (CRF_T - 1)] = (float)bi;
        int E = bi;                    // exit tag of segment 15 (t=1023)
        s_E[NSEG - 1] = E;
        for (int s = NSEG - 1; s >= 1; --s) { E = lmap[s][E]; s_E[s - 1] = E; }
    }
    __syncthreads();

    // Phase 3: re-chase; winner emits
    for (int s = 0; s < NSEG; ++s) {
        const int rows = (s == NSEG - 1) ? SEGLEN - 1 : SEGLEN;
        const int r0   = s * SEGLEN;
        const int nw   = rows * 64;
        for (int w = tid; w < nw; w += 256) {
            const int r = w >> 6, cc = w & 63;
            ((unsigned int*)lbp[r])[cc] =
                ((const unsigned int*)(bpb + (size_t)(r0 + r) * CRF_K))[cc];
        }
        __syncthreads();
        int tag = tid;
        const bool win = (tid == s_E[s]);
        for (int j = rows - 1; j >= 0; --j) {
            tag = lbp[j][tag];                       // tag @ time r0+j
            if (win) out[(size_t)b * CRF_T + r0 + j] = (float)tag;
        }
        __syncthreads();
    }
}

// ---------------------------------------------------------------------------
// Fallback path (PROVEN round-2): transpose + serial backtrack.
// ---------------------------------------------------------------------------

__global__ void crf_transpose_trans(const float* __restrict__ trans,
                                    float* __restrict__ Tt)
{
    const int k = blockIdx.x;
    const int p = threadIdx.x;
    Tt[(size_t)k * CRF_K + p] = trans[(size_t)p * CRF_K + k];
}

__device__ __forceinline__ int wave_argmax(float v, int i)
{
#pragma unroll
    for (int off = 32; off >= 1; off >>= 1) {
        float ov = __shfl_xor(v, off, 64);
        int   oi = __shfl_xor(i, off, 64);
        if (ov > v || (ov == v && oi < i)) { v = ov; i = oi; }
    }
    return i;
}

__device__ __forceinline__ int step_argmax(float4 sv, float4 tv, int base)
{
    float s0 = sv.x + tv.x, s1 = sv.y + tv.y;
    float s2 = sv.z + tv.z, s3 = sv.w + tv.w;
    float nbv = s0; int nbi = base;
    if (s1 > nbv) { nbv = s1; nbi = base + 1; }
    if (s2 > nbv) { nbv = s2; nbi = base + 2; }
    if (s3 > nbv) { nbv = s3; nbi = base + 3; }
    return wave_argmax(nbv, nbi);
}

__global__ __launch_bounds__(64) void crf_backtrack_states(
    const float* __restrict__ states, const float* __restrict__ Tt,
    float* __restrict__ out)
{
    const int b    = blockIdx.x;
    const int lane = threadIdx.x;
    const int base = lane * 4;

    const float4* stb =
        (const float4*)(states + ((size_t)(CRF_T - 1) * CRF_B + b) * CRF_K);
    float4 v = stb[lane];
    float bv = v.x; int bi = base;
    if (v.y > bv) { bv = v.y; bi = base + 1; }
    if (v.z > bv) { bv = v.z; bi = base + 2; }
    if (v.w > bv) { bv = v.w; bi = base + 3; }
    int tag = wave_argmax(bv, bi);
    if (lane == 0) out[(size_t)b * CRF_T + (CRF_T - 1)] = (float)tag;

    float* ob = out + (size_t)b * CRF_T;
    int t = CRF_T - 1;
    for (; t >= 4; t -= 4) {
        float4 sv0 = ((const float4*)(states + ((size_t)(t - 1) * CRF_B + b) * CRF_K))[lane];
        float4 sv1 = ((const float4*)(states + ((size_t)(t - 2) * CRF_B + b) * CRF_K))[lane];
        float4 sv2 = ((const float4*)(states + ((size_t)(t - 3) * CRF_B + b) * CRF_K))[lane];
        float4 sv3 = ((const float4*)(states + ((size_t)(t - 4) * CRF_B + b) * CRF_K))[lane];

        float4 tv = ((const float4*)(Tt + (size_t)tag * CRF_K))[lane];
        tag = step_argmax(sv0, tv, base);
        if (lane == 0) ob[t - 1] = (float)tag;
        tv = ((const float4*)(Tt + (size_t)tag * CRF_K))[lane];
        tag = step_argmax(sv1, tv, base);
        if (lane == 0) ob[t - 2] = (float)tag;
        tv = ((const float4*)(Tt + (size_t)tag * CRF_K))[lane];
        tag = step_argmax(sv2, tv, base);
        if (lane == 0) ob[t - 3] = (float)tag;
        tv = ((const float4*)(Tt + (size_t)tag * CRF_K))[lane];
        tag = step_argmax(sv3, tv, base);
        if (lane == 0) ob[t - 4] = (float)tag;
    }
    for (; t >= 1; --t) {
        float4 sv = ((const float4*)(states + ((size_t)(t - 1) * CRF_B + b) * CRF_K))[lane];
        float4 tv = ((const float4*)(Tt + (size_t)tag * CRF_K))[lane];
        tag = step_argmax(sv, tv, base);
        if (lane == 0) ob[t - 1] = (float)tag;
    }
}

__global__ void crf_zero_out(float* __restrict__ out, int n)
{
    int i = blockIdx.x * blockDim.x + threadIdx.x;
    if (i < n) out[i] = 0.0f;
}

// ---------------------------------------------------------------------------

extern "C" void kernel_launch(void* const* d_in, const int* in_sizes, int n_in,
                              void* d_out, int out_size, void* d_ws, size_t ws_size,
                              hipStream_t stream) {
    (void)in_sizes; (void)n_in;
    const float* em    = (const float*)d_in[0];   // [B,T,K]
    const float* trans = (const float*)d_in[1];   // [K,K]
    float* out = (float*)d_out;                   // [B,T]

    const size_t states_bytes = (size_t)CRF_T * CRF_B * CRF_K * sizeof(float); // 64 MB
    const size_t bp_bytes     = (size_t)CRF_B * (CRF_T - 1) * CRF_K;           // ~16 MB
    const size_t tt_bytes     = (size_t)CRF_K * CRF_K * sizeof(float);         // 256 KB

    if (ws_size >= states_bytes + bp_bytes) {
        float*         states = (float*)d_ws;
        unsigned char* bp     = (unsigned char*)((char*)d_ws + states_bytes);
        crf_forward_states<<<CRF_B, 1024, 0, stream>>>(em, trans, states);
        crf_bp_matrix<<<CRF_B * NSEG, 1024, 0, stream>>>(states, trans, bp);
        crf_backtrack<<<CRF_B, 256, 0, stream>>>(states, bp, out);
    } else if (ws_size >= states_bytes + tt_bytes) {
        float* states = (float*)d_ws;
        float* Tt     = (float*)((char*)d_ws + states_bytes);
        crf_transpose_trans<<<CRF_K, CRF_K, 0, stream>>>(trans, Tt);
        crf_forward_states<<<CRF_B, 1024, 0, stream>>>(em, trans, states);
        crf_backtrack_states<<<CRF_B, 64, 0, stream>>>(states, Tt, out);
    } else {
        crf_zero_out<<<(out_size + 255) / 256, 256, 0, stream>>>(out, out_size);
    }
}

// Round 5
// 1351.551 us; speedup vs baseline: 1.2770x; 1.0712x over previous
//
#include <hip/hip_runtime.h>

// CRF Viterbi decode: B=64, T=1024, K=256.
// emissions [B,T,K] f32, transitions [K,K] f32 (prev->next). out [B,T] f32 tags.
//
// Path A (states 64MB + bp 16MB + maps 256KB + exits 4KB):
//   1. crf_forward_states : proven round-2 kernel + __launch_bounds__(1024,4)
//      (single-token change: kill the trans-slice spill seen at VGPR=48).
//   2. crf_bp_matrix      : proven round-4 kernel (unchanged).
//   3. crf_seg_maps       : 1024 blocks: per (b,seg) chase all 256 candidates
//      through LDS bp rows -> entry maps (parallel, was serial in round 4).
//   4. crf_compose        : 64 blocks: final-state argmax + 16 map hops.
//   5. crf_emit           : 1024 blocks: re-chase, winner thread writes tags.
// Path B (states+bp): round-4 proven monolithic backtrack.
// Path C (states+Tt): round-2 proven serial backtrack.

#define CRF_B 64
#define CRF_T 1024
#define CRF_K 256
#define NSEG  16
#define SEGLEN 64

#define FG 8
#define FP 32
#define FC 8

// ---------------------------------------------------------------------------
// Forward (round-2 proven; ONLY change: ",4" in launch_bounds)
// ---------------------------------------------------------------------------

__global__ __launch_bounds__(1024, 4) void crf_forward_states(
    const float* __restrict__ em, const float* __restrict__ trans,
    float* __restrict__ states)
{
    const int b   = blockIdx.x;
    const int tid = threadIdx.x;
    const int g   = tid >> 7;      // prev group 0..7
    const int c   = tid & 127;     // columns c and c+128

    __shared__ __align__(16) float s_state[CRF_K];
    __shared__ float s_partial[FG][CRF_K];

    const int pbase = g * FP;

    float4 t0[FC], t1[FC];
#pragma unroll
    for (int i = 0; i < FC; ++i) {
        const int p = pbase + 4 * i;
        t0[i].x = trans[(p + 0) * CRF_K + c];
        t0[i].y = trans[(p + 1) * CRF_K + c];
        t0[i].z = trans[(p + 2) * CRF_K + c];
        t0[i].w = trans[(p + 3) * CRF_K + c];
        t1[i].x = trans[(p + 0) * CRF_K + c + 128];
        t1[i].y = trans[(p + 1) * CRF_K + c + 128];
        t1[i].z = trans[(p + 2) * CRF_K + c + 128];
        t1[i].w = trans[(p + 3) * CRF_K + c + 128];
    }
#pragma unroll
    for (int i = 0; i < FC; ++i) {
        asm volatile("" : "+v"(t0[i].x), "+v"(t0[i].y), "+v"(t0[i].z), "+v"(t0[i].w));
        asm volatile("" : "+v"(t1[i].x), "+v"(t1[i].y), "+v"(t1[i].z), "+v"(t1[i].w));
    }

    const float* emb = em + (size_t)b * CRF_T * CRF_K;
    if (tid < CRF_K) {
        float v = emb[tid];
        s_state[tid] = v;
        states[(size_t)b * CRF_K + tid] = v;   // t = 0
    }
    __syncthreads();

    for (int t = 1; t < CRF_T; ++t) {
        float e = 0.0f;
        if (tid < CRF_K) e = emb[t * CRF_K + tid];

        float b0 = -INFINITY, b1 = -INFINITY;
        const float4* sp = (const float4*)(s_state + pbase);
#pragma unroll
        for (int i = 0; i < FC; ++i) {
            float4 st = sp[i];
            float a0 = st.x + t0[i].x;
            float a1 = st.y + t0[i].y;
            float a2 = st.z + t0[i].z;
            float a3 = st.w + t0[i].w;
            b0 = fmaxf(b0, fmaxf(fmaxf(a0, a1), fmaxf(a2, a3)));
            float c0 = st.x + t1[i].x;
            float c1 = st.y + t1[i].y;
            float c2 = st.z + t1[i].z;
            float c3 = st.w + t1[i].w;
            b1 = fmaxf(b1, fmaxf(fmaxf(c0, c1), fmaxf(c2, c3)));
        }
        s_partial[g][c]       = b0;
        s_partial[g][c + 128] = b1;
        __syncthreads();
        if (tid < CRF_K) {
            float m = s_partial[0][tid];
#pragma unroll
            for (int j = 1; j < FG; ++j) m = fmaxf(m, s_partial[j][tid]);
            float v = m + e;
            s_state[tid] = v;
            states[((size_t)t * CRF_B + b) * CRF_K + tid] = v;
        }
        __syncthreads();
    }
}

// ---------------------------------------------------------------------------
// Backpointer matrix (round-4 proven, unchanged)
// ---------------------------------------------------------------------------

__global__ __launch_bounds__(1024, 2) void crf_bp_matrix(
    const float* __restrict__ states, const float* __restrict__ trans,
    unsigned char* __restrict__ bp)
{
    const int b   = blockIdx.x >> 4;
    const int seg = blockIdx.x & 15;
    const int tid = threadIdx.x;
    const int g   = tid >> 8;      // 0..3
    const int k   = tid & 255;

    __shared__ __align__(16) float s_row[CRF_K];
    __shared__ float s_pv[4][CRF_K];
    __shared__ int   s_pi[4][CRF_K];

    const int pbase = g * 64;
    float4 tr[16];
#pragma unroll
    for (int i = 0; i < 16; ++i) {
        const int p = pbase + 4 * i;
        tr[i].x = trans[(p + 0) * CRF_K + k];
        tr[i].y = trans[(p + 1) * CRF_K + k];
        tr[i].z = trans[(p + 2) * CRF_K + k];
        tr[i].w = trans[(p + 3) * CRF_K + k];
        asm volatile("" : "+v"(tr[i].x), "+v"(tr[i].y), "+v"(tr[i].z), "+v"(tr[i].w));
    }

    const int t_lo = seg * SEGLEN;
    const int t_hi = min(t_lo + SEGLEN, CRF_T - 1);   // bp rows 0..1022

    unsigned char* bpb = bp + (size_t)b * (CRF_T - 1) * CRF_K;

    for (int t1 = t_lo; t1 < t_hi; ++t1) {
        if (tid < CRF_K)
            s_row[tid] = states[((size_t)t1 * CRF_B + b) * CRF_K + tid];
        __syncthreads();

        float best = -INFINITY;
        int   arg  = pbase;
        const float4* sp = (const float4*)(s_row + pbase);
#pragma unroll
        for (int i = 0; i < 16; ++i) {
            float4 st = sp[i];
            const int p = pbase + 4 * i;
            float s0 = st.x + tr[i].x;
            float s1 = st.y + tr[i].y;
            float s2 = st.z + tr[i].z;
            float s3 = st.w + tr[i].w;
            if (s0 > best) { best = s0; arg = p; }
            if (s1 > best) { best = s1; arg = p + 1; }
            if (s2 > best) { best = s2; arg = p + 2; }
            if (s3 > best) { best = s3; arg = p + 3; }
        }
        s_pv[g][k] = best;
        s_pi[g][k] = arg;
        __syncthreads();
        if (tid < CRF_K) {
            float bv = s_pv[0][tid];
            int   ba = s_pi[0][tid];
#pragma unroll
            for (int j = 1; j < 4; ++j) {
                float v = s_pv[j][tid];
                if (v > bv) { bv = v; ba = s_pi[j][tid]; }
            }
            bpb[(size_t)t1 * CRF_K + tid] = (unsigned char)ba;
        }
        __syncthreads();
    }
}

// ---------------------------------------------------------------------------
// Parallel backtrack (NEW): seg_maps -> compose -> emit.
// Same chase/compose logic as round-4 monolithic, split across blocks.
// ---------------------------------------------------------------------------

__global__ __launch_bounds__(256) void crf_seg_maps(
    const unsigned char* __restrict__ bp, unsigned char* __restrict__ maps)
{
    const int b   = blockIdx.x >> 4;
    const int s   = blockIdx.x & 15;
    const int tid = threadIdx.x;
    const int rows = (s == NSEG - 1) ? SEGLEN - 1 : SEGLEN;
    const int r0   = s * SEGLEN;

    __shared__ unsigned char lbp[SEGLEN][CRF_K];   // 16 KB

    const unsigned char* bpb = bp + (size_t)b * (CRF_T - 1) * CRF_K;
    const int nw = rows * 64;
    for (int w = tid; w < nw; w += 256) {
        const int r = w >> 6, cc = w & 63;
        ((unsigned int*)lbp[r])[cc] =
            ((const unsigned int*)(bpb + (size_t)(r0 + r) * CRF_K))[cc];
    }
    __syncthreads();

    int tag = tid;   // candidate tag at segment exit (t = r0 + rows)
    for (int j = rows - 1; j >= 0; --j) tag = lbp[j][tag];
    maps[((size_t)b * NSEG + s) * CRF_K + tid] = (unsigned char)tag;
}

__global__ __launch_bounds__(256) void crf_compose(
    const float* __restrict__ states, const unsigned char* __restrict__ maps,
    int* __restrict__ exits, float* __restrict__ out)
{
    const int b   = blockIdx.x;
    const int tid = threadIdx.x;

    __shared__ float s_wv[4];
    __shared__ int   s_wi[4];

    float v = states[((size_t)(CRF_T - 1) * CRF_B + b) * CRF_K + tid];
    int   i = tid;
#pragma unroll
    for (int off = 32; off >= 1; off >>= 1) {
        float ov = __shfl_xor(v, off, 64);
        int   oi = __shfl_xor(i, off, 64);
        if (ov > v || (ov == v && oi < i)) { v = ov; i = oi; }
    }
    const int lane = tid & 63, wv = tid >> 6;
    if (lane == 0) { s_wv[wv] = v; s_wi[wv] = i; }
    __syncthreads();
    if (tid == 0) {
        float bv = s_wv[0]; int bi = s_wi[0];
#pragma unroll
        for (int w = 1; w < 4; ++w)
            if (s_wv[w] > bv) { bv = s_wv[w]; bi = s_wi[w]; }
        out[(size_t)b * CRF_T + (CRF_T - 1)] = (float)bi;
        int E = bi;                       // tag at t=1023 (exit of seg 15)
        exits[b * NSEG + NSEG - 1] = E;
        const unsigned char* mb = maps + (size_t)b * NSEG * CRF_K;
        for (int s = NSEG - 1; s >= 1; --s) {
            E = mb[(size_t)s * CRF_K + E];   // tag at t = s*64
            exits[b * NSEG + s - 1] = E;     // exit tag of segment s-1
        }
    }
}

__global__ __launch_bounds__(256) void crf_emit(
    const unsigned char* __restrict__ bp, const int* __restrict__ exits,
    float* __restrict__ out)
{
    const int b   = blockIdx.x >> 4;
    const int s   = blockIdx.x & 15;
    const int tid = threadIdx.x;
    const int rows = (s == NSEG - 1) ? SEGLEN - 1 : SEGLEN;
    const int r0   = s * SEGLEN;

    __shared__ unsigned char lbp[SEGLEN][CRF_K];

    const unsigned char* bpb = bp + (size_t)b * (CRF_T - 1) * CRF_K;
    const int nw = rows * 64;
    for (int w = tid; w < nw; w += 256) {
        const int r = w >> 6, cc = w & 63;
        ((unsigned int*)lbp[r])[cc] =
            ((const unsigned int*)(bpb + (size_t)(r0 + r) * CRF_K))[cc];
    }
    __syncthreads();

    int tag = tid;
    const bool win = (tid == exits[b * NSEG + s]);
    for (int j = rows - 1; j >= 0; --j) {
        tag = lbp[j][tag];                           // tag @ t = r0 + j
        if (win) out[(size_t)b * CRF_T + r0 + j] = (float)tag;
    }
}

// ---------------------------------------------------------------------------
// Fallback B: round-4 proven monolithic backtrack.
// ---------------------------------------------------------------------------

__global__ __launch_bounds__(256) void crf_backtrack(
    const float* __restrict__ states, const unsigned char* __restrict__ bp,
    float* __restrict__ out)
{
    const int b   = blockIdx.x;
    const int tid = threadIdx.x;

    __shared__ unsigned char lbp[SEGLEN][CRF_K];
    __shared__ unsigned char lmap[NSEG][CRF_K];
    __shared__ int   s_E[NSEG];
    __shared__ float s_wv[4];
    __shared__ int   s_wi[4];

    const unsigned char* bpb = bp + (size_t)b * (CRF_T - 1) * CRF_K;

    for (int s = 0; s < NSEG; ++s) {
        const int rows = (s == NSEG - 1) ? SEGLEN - 1 : SEGLEN;
        const int r0   = s * SEGLEN;
        const int nw   = rows * 64;
        for (int w = tid; w < nw; w += 256) {
            const int r = w >> 6, cc = w & 63;
            ((unsigned int*)lbp[r])[cc] =
                ((const unsigned int*)(bpb + (size_t)(r0 + r) * CRF_K))[cc];
        }
        __syncthreads();
        int tag = tid;
        for (int j = rows - 1; j >= 0; --j) tag = lbp[j][tag];
        lmap[s][tid] = (unsigned char)tag;
        __syncthreads();
    }

    float v = states[((size_t)(CRF_T - 1) * CRF_B + b) * CRF_K + tid];
    int   i = tid;
#pragma unroll
    for (int off = 32; off >= 1; off >>= 1) {
        float ov = __shfl_xor(v, off, 64);
        int   oi = __shfl_xor(i, off, 64);
        if (ov > v || (ov == v && oi < i)) { v = ov; i = oi; }
    }
    const int lane = tid & 63, wv = tid >> 6;
    if (lane == 0) { s_wv[wv] = v; s_wi[wv] = i; }
    __syncthreads();
    if (tid == 0) {
        float bv = s_wv[0]; int bi = s_wi[0];
#pragma unroll
        for (int w = 1; w < 4; ++w)
            if (s_wv[w] > bv) { bv = s_wv[w]; bi = s_wi[w]; }
        out[(size_t)b * CRF_T + (CRF_T - 1)] = (float)bi;
        int E = bi;
        s_E[NSEG - 1] = E;
        for (int s = NSEG - 1; s >= 1; --s) { E = lmap[s][E]; s_E[s - 1] = E; }
    }
    __syncthreads();

    for (int s = 0; s < NSEG; ++s) {
        const int rows = (s == NSEG - 1) ? SEGLEN - 1 : SEGLEN;
        const int r0   = s * SEGLEN;
        const int nw   = rows * 64;
        for (int w = tid; w < nw; w += 256) {
            const int r = w >> 6, cc = w & 63;
            ((unsigned int*)lbp[r])[cc] =
                ((const unsigned int*)(bpb + (size_t)(r0 + r) * CRF_K))[cc];
        }
        __syncthreads();
        int tag = tid;
        const bool win = (tid == s_E[s]);
        for (int j = rows - 1; j >= 0; --j) {
            tag = lbp[j][tag];
            if (win) out[(size_t)b * CRF_T + r0 + j] = (float)tag;
        }
        __syncthreads();
    }
}

// ---------------------------------------------------------------------------
// Fallback C: round-2 proven serial backtrack.
// ---------------------------------------------------------------------------

__global__ void crf_transpose_trans(const float* __restrict__ trans,
                                    float* __restrict__ Tt)
{
    const int k = blockIdx.x;
    const int p = threadIdx.x;
    Tt[(size_t)k * CRF_K + p] = trans[(size_t)p * CRF_K + k];
}

__device__ __forceinline__ int wave_argmax(float v, int i)
{
#pragma unroll
    for (int off = 32; off >= 1; off >>= 1) {
        float ov = __shfl_xor(v, off, 64);
        int   oi = __shfl_xor(i, off, 64);
        if (ov > v || (ov == v && oi < i)) { v = ov; i = oi; }
    }
    return i;
}

__device__ __forceinline__ int step_argmax(float4 sv, float4 tv, int base)
{
    float s0 = sv.x + tv.x, s1 = sv.y + tv.y;
    float s2 = sv.z + tv.z, s3 = sv.w + tv.w;
    float nbv = s0; int nbi = base;
    if (s1 > nbv) { nbv = s1; nbi = base + 1; }
    if (s2 > nbv) { nbv = s2; nbi = base + 2; }
    if (s3 > nbv) { nbv = s3; nbi = base + 3; }
    return wave_argmax(nbv, nbi);
}

__global__ __launch_bounds__(64) void crf_backtrack_states(
    const float* __restrict__ states, const float* __restrict__ Tt,
    float* __restrict__ out)
{
    const int b    = blockIdx.x;
    const int lane = threadIdx.x;
    const int base = lane * 4;

    const float4* stb =
        (const float4*)(states + ((size_t)(CRF_T - 1) * CRF_B + b) * CRF_K);
    float4 v = stb[lane];
    float bv = v.x; int bi = base;
    if (v.y > bv) { bv = v.y; bi = base + 1; }
    if (v.z > bv) { bv = v.z; bi = base + 2; }
    if (v.w > bv) { bv = v.w; bi = base + 3; }
    int tag = wave_argmax(bv, bi);
    if (lane == 0) out[(size_t)b * CRF_T + (CRF_T - 1)] = (float)tag;

    float* ob = out + (size_t)b * CRF_T;
    int t = CRF_T - 1;
    for (; t >= 4; t -= 4) {
        float4 sv0 = ((const float4*)(states + ((size_t)(t - 1) * CRF_B + b) * CRF_K))[lane];
        float4 sv1 = ((const float4*)(states + ((size_t)(t - 2) * CRF_B + b) * CRF_K))[lane];
        float4 sv2 = ((const float4*)(states + ((size_t)(t - 3) * CRF_B + b) * CRF_K))[lane];
        float4 sv3 = ((const float4*)(states + ((size_t)(t - 4) * CRF_B + b) * CRF_K))[lane];

        float4 tv = ((const float4*)(Tt + (size_t)tag * CRF_K))[lane];
        tag = step_argmax(sv0, tv, base);
        if (lane == 0) ob[t - 1] = (float)tag;
        tv = ((const float4*)(Tt + (size_t)tag * CRF_K))[lane];
        tag = step_argmax(sv1, tv, base);
        if (lane == 0) ob[t - 2] = (float)tag;
        tv = ((const float4*)(Tt + (size_t)tag * CRF_K))[lane];
        tag = step_argmax(sv2, tv, base);
        if (lane == 0) ob[t - 3] = (float)tag;
        tv = ((const float4*)(Tt + (size_t)tag * CRF_K))[lane];
        tag = step_argmax(sv3, tv, base);
        if (lane == 0) ob[t - 4] = (float)tag;
    }
    for (; t >= 1; --t) {
        float4 sv = ((const float4*)(states + ((size_t)(t - 1) * CRF_B + b) * CRF_K))[lane];
        float4 tv = ((const float4*)(Tt + (size_t)tag * CRF_K))[lane];
        tag = step_argmax(sv, tv, base);
        if (lane == 0) ob[t - 1] = (float)tag;
    }
}

__global__ void crf_zero_out(float* __restrict__ out, int n)
{
    int i = blockIdx.x * blockDim.x + threadIdx.x;
    if (i < n) out[i] = 0.0f;
}

// ---------------------------------------------------------------------------

extern "C" void kernel_launch(void* const* d_in, const int* in_sizes, int n_in,
                              void* d_out, int out_size, void* d_ws, size_t ws_size,
                              hipStream_t stream) {
    (void)in_sizes; (void)n_in;
    const float* em    = (const float*)d_in[0];   // [B,T,K]
    const float* trans = (const float*)d_in[1];   // [K,K]
    float* out = (float*)d_out;                   // [B,T]

    const size_t states_bytes = (size_t)CRF_T * CRF_B * CRF_K * sizeof(float); // 64 MB
    const size_t bp_bytes     = (size_t)CRF_B * (CRF_T - 1) * CRF_K;           // ~16 MB
    const size_t maps_bytes   = (size_t)CRF_B * NSEG * CRF_K;                  // 256 KB
    const size_t exits_bytes  = (size_t)CRF_B * NSEG * sizeof(int);            // 4 KB
    const size_t tt_bytes     = (size_t)CRF_K * CRF_K * sizeof(float);         // 256 KB

    char* w = (char*)d_ws;
    if (ws_size >= states_bytes + bp_bytes + maps_bytes + exits_bytes) {
        float*         states = (float*)w;            w += states_bytes;
        unsigned char* bp     = (unsigned char*)w;    w += bp_bytes;
        unsigned char* maps   = (unsigned char*)w;    w += maps_bytes;
        int*           exits  = (int*)w;

        crf_forward_states<<<CRF_B, 1024, 0, stream>>>(em, trans, states);
        crf_bp_matrix<<<CRF_B * NSEG, 1024, 0, stream>>>(states, trans, bp);
        crf_seg_maps<<<CRF_B * NSEG, 256, 0, stream>>>(bp, maps);
        crf_compose<<<CRF_B, 256, 0, stream>>>(states, maps, exits, out);
        crf_emit<<<CRF_B * NSEG, 256, 0, stream>>>(bp, exits, out);
    } else if (ws_size >= states_bytes + bp_bytes) {
        float*         states = (float*)d_ws;
        unsigned char* bp     = (unsigned char*)((char*)d_ws + states_bytes);
        crf_forward_states<<<CRF_B, 1024, 0, stream>>>(em, trans, states);
        crf_bp_matrix<<<CRF_B * NSEG, 1024, 0, stream>>>(states, trans, bp);
        crf_backtrack<<<CRF_B, 256, 0, stream>>>(states, bp, out);
    } else if (ws_size >= states_bytes + tt_bytes) {
        float* states = (float*)d_ws;
        float* Tt     = (float*)((char*)d_ws + states_bytes);
        crf_transpose_trans<<<CRF_K, CRF_K, 0, stream>>>(trans, Tt);
        crf_forward_states<<<CRF_B, 1024, 0, stream>>>(em, trans, states);
        crf_backtrack_states<<<CRF_B, 64, 0, stream>>>(states, Tt, out);
    } else {
        crf_zero_out<<<(out_size + 255) / 256, 256, 0, stream>>>(out, out_size);
    }
}